// Round 1
// 265.276 us; speedup vs baseline: 1.0040x; 1.0040x over previous
//
#include <hip/hip_runtime.h>

#define KN 12
#define DNBR 320
#define DNEW 256
#define BN_TOT 8192
#define ATB 2                 // atoms per block
#define NKS_E 10              // 320/32
#define NKS_H 8               // 256/32
#define ASTR_E 328            // A_e row stride in u16 (320 + 8 pad)
#define ASTR_H 264            // A_h row stride in u16 (256 + 8 pad)
#define H_OFF 294912          // byte offset of precomputed h in workspace (after B2)

typedef short bf8_t __attribute__((ext_vector_type(8)));
typedef float f32x4 __attribute__((ext_vector_type(4)));
typedef unsigned short us8 __attribute__((ext_vector_type(8)));
using u16 = unsigned short;
using u32 = unsigned int;

__device__ __forceinline__ u16 f2bf(float f) {
    u32 x = __float_as_uint(f);
    return (u16)((x + 0x7fffu + ((x >> 16) & 1u)) >> 16);  // RNE
}

__device__ __forceinline__ us8 pack8(float4 a, float4 b) {
    us8 v;
    v[0] = f2bf(a.x); v[1] = f2bf(a.y); v[2] = f2bf(a.z); v[3] = f2bf(a.w);
    v[4] = f2bf(b.x); v[5] = f2bf(b.y); v[6] = f2bf(b.z); v[7] = f2bf(b.w);
    return v;
}

// ---- kernel 1: fragment-major stacked B2: tiles 0..159 = Wn (10 ks x 16 nt),
// tiles 160..287 = Wa (8 ks x 16 nt). Tile = 64 lanes x 8 u16 (1KB). ----
__global__ __launch_bounds__(256) void build_b2(
    const float* __restrict__ Wn, const float* __restrict__ Wa,
    u16* __restrict__ B2)
{
    int tile = blockIdx.x * 4 + (threadIdx.x >> 6);   // 0..287
    int l = threadIdx.x & 63;
    int q = l >> 4, m = l & 15;
    us8 v;
    if (tile < 160) {
        int ks = tile >> 4, nt = tile & 15;
        int col = nt * 16 + m;
#pragma unroll
        for (int e = 0; e < 8; e++)
            v[e] = f2bf(Wn[(ks * 32 + q * 8 + e) * DNEW + col]);
    } else {
        int tt = tile - 160;
        int ks = tt >> 4, nt = tt & 15;
        int col = nt * 16 + m;
#pragma unroll
        for (int e = 0; e < 8; e++)
            v[e] = f2bf(Wa[(ks * 32 + q * 8 + e) * DNEW + col]);
    }
    *(us8*)&B2[(size_t)tile * 512 + l * 8] = v;
}

// ---- kernel 2: precompute h = atomf @ Wa + ba, fp32 to workspace. 32 atoms/block. ----
__global__ __launch_bounds__(256) void h_pre(
    const float* __restrict__ atomf, const u16* __restrict__ B2,
    const float* __restrict__ ba, float* __restrict__ h_g)
{
    __shared__ u16 A[32 * ASTR_H];   // 16896 B

    const int t = threadIdx.x;
    const int l = t & 63, w = t >> 6, q = l >> 4, m = l & 15;
    const int ab = blockIdx.x * 32;

    // stage 32 atoms x 256 f32 -> bf16 (1024 us8 chunks)
    const float* base = atomf + (size_t)ab * DNEW;
    for (int i = t; i < 1024; i += 256) {
        float4 v0 = *(const float4*)(base + i * 8);
        float4 v1 = *(const float4*)(base + i * 8 + 4);
        int a = i >> 5, c8 = i & 31;
        *(us8*)&A[a * ASTR_H + c8 * 8] = pack8(v0, v1);
    }
    __syncthreads();

    f32x4 acc[2][4];
#pragma unroll
    for (int mt = 0; mt < 2; mt++)
#pragma unroll
        for (int j = 0; j < 4; j++) acc[mt][j] = (f32x4){0.f, 0.f, 0.f, 0.f};

    for (int ks = 0; ks < NKS_H; ks++) {
        bf8_t af0 = *(bf8_t*)&A[m * ASTR_H + ks * 32 + q * 8];
        bf8_t af1 = *(bf8_t*)&A[(16 + m) * ASTR_H + ks * 32 + q * 8];
#pragma unroll
        for (int j = 0; j < 4; j++) {
            bf8_t bfj = *(const bf8_t*)&B2[((size_t)(160 + ks * 16 + w * 4 + j) * 64 + l) * 8];
            acc[0][j] = __builtin_amdgcn_mfma_f32_16x16x32_bf16(af0, bfj, acc[0][j], 0, 0, 0);
            acc[1][j] = __builtin_amdgcn_mfma_f32_16x16x32_bf16(af1, bfj, acc[1][j], 0, 0, 0);
        }
    }
#pragma unroll
    for (int mt = 0; mt < 2; mt++)
#pragma unroll
        for (int j = 0; j < 4; j++) {
            int col = w * 64 + j * 16 + m;
            float bav = ba[col];
#pragma unroll
            for (int r = 0; r < 4; r++) {
                int row = ab + mt * 16 + q * 4 + r;
                h_g[(size_t)row * DNEW + col] = acc[mt][j][r] + bav;
            }
        }
}

// ---- kernel 3: fused e-GEMM + GATv2 attention + LN. 2 atoms/block.
// A_e: 28 rows (atom0 nbrs 0-11 = rows 0-11, atom1 = rows 12-23, zero pad 24-27).
// Scores/softmax/attn/ctx are register+shuffle only (wave-local); 2 barriers total. ----
__global__ __launch_bounds__(256, 6) void fused_all(
    const float* __restrict__ nbrf,
    const float* __restrict__ smaskg, const float* __restrict__ amaskg,
    const u16* __restrict__ B2, const float* __restrict__ h_g,
    const float* __restrict__ bnb, const float* __restrict__ walg,
    const float* __restrict__ balg, const float* __restrict__ gam,
    const float* __restrict__ bet, float* __restrict__ out)
{
    __shared__ u16 A_e[28 * ASTR_E];         // 18368 B
    __shared__ float bnb_l[256];             // 1024 B
    __shared__ float wal_l[32];              // 128 B
    __shared__ float smask_l[ATB * KN];      // 96 B (includes b_align)
    __shared__ float amask_l[ATB * KN];      // 96 B
    __shared__ float red_l[ATB][8];          // 64 B

    const int t = threadIdx.x;
    const int l = t & 63, w = t >> 6, q = l >> 4, m = l & 15;
    const int a0 = blockIdx.x * ATB;

    // ---- params ----
    bnb_l[t] = bnb[t];
    if (t < 32) wal_l[t] = walg[t];
    else if (t >= 32 && t < 32 + ATB * KN)
        smask_l[t - 32] = smaskg[(size_t)a0 * KN + (t - 32)] + balg[0];
    else if (t >= 64 && t < 64 + ATB * KN)
        amask_l[t - 64] = amaskg[(size_t)a0 * KN + (t - 64)];

    // ---- stage nbr -> A_e rows 0..23 (960 us8 chunks) ----
    const float* nbase = nbrf + (size_t)a0 * (KN * DNBR);
    for (int i = t; i < 960; i += 256) {
        float4 v0 = *(const float4*)(nbase + i * 8);
        float4 v1 = *(const float4*)(nbase + i * 8 + 4);
        int at = i / 480, rem = i - at * 480;
        int row = rem / 40, c8 = rem - row * 40;
        *(us8*)&A_e[(at * 12 + row) * ASTR_E + c8 * 8] = pack8(v0, v1);
    }
    // ---- zero pad rows 24..27 (read as tile-1 rows m=12..15; attn weight there is 0,
    // but must be finite so 0*x doesn't NaN) ----
    if (t < 164) {
        int rr = t / 41, c8 = t - rr * 41;
        us8 z = {0, 0, 0, 0, 0, 0, 0, 0};
        *(us8*)&A_e[(24 + rr) * ASTR_E + c8 * 8] = z;
    }

    // ---- h loads from workspace (issued early; independent of LDS) ----
    float hv[ATB][4];
#pragma unroll
    for (int j = 0; j < 4; j++) {
        int col = w * 64 + j * 16 + m;
        hv[0][j] = h_g[(size_t)(a0 + 0) * DNEW + col];
        hv[1][j] = h_g[(size_t)(a0 + 1) * DNEW + col];
    }

    __syncthreads();   // barrier 1: A_e staged

    // ---- e-GEMM: acc_e[at][j] over cols w*64+j*16+m, rows (at*12 + q*4 + r) ----
    f32x4 acc_e[ATB][4];
#pragma unroll
    for (int at = 0; at < ATB; at++)
#pragma unroll
        for (int j = 0; j < 4; j++) acc_e[at][j] = (f32x4){0.f, 0.f, 0.f, 0.f};

    for (int ks = 0; ks < NKS_E; ks++) {
        bf8_t af0 = *(bf8_t*)&A_e[m * ASTR_E + ks * 32 + q * 8];
        bf8_t af1 = *(bf8_t*)&A_e[(12 + m) * ASTR_E + ks * 32 + q * 8];
#pragma unroll
        for (int j = 0; j < 4; j++) {
            bf8_t bfj = *(const bf8_t*)&B2[((size_t)(ks * 16 + w * 4 + j) * 64 + l) * 8];
            acc_e[0][j] = __builtin_amdgcn_mfma_f32_16x16x32_bf16(af0, bfj, acc_e[0][j], 0, 0, 0);
            acc_e[1][j] = __builtin_amdgcn_mfma_f32_16x16x32_bf16(af1, bfj, acc_e[1][j], 0, 0, 0);
        }
    }

    // ---- e_reg = acc_e + bnb (true e) ----
#pragma unroll
    for (int j = 0; j < 4; j++) {
        float bv = bnb_l[w * 64 + j * 16 + m];
#pragma unroll
        for (int at = 0; at < ATB; at++)
#pragma unroll
            for (int r = 0; r < 4; r++) acc_e[at][j][r] += bv;
    }

    float wv[4];
#pragma unroll
    for (int j = 0; j < 4; j++) wv[j] = wal_l[(j * 16 + m) & 31];

    // ---- scores + softmax + attn + ctx: all wave-local (wave w owns heads 2w,2w+1) ----
    float ctxv[ATB][4];
#pragma unroll
    for (int at = 0; at < ATB; at++) {
        float s1 = 0.f, s2 = 0.f;
#pragma unroll
        for (int jj = 0; jj < 2; jj++) {
            // scores: p[r] for neighbor k = q*4+r (q==3 rows are pad -> masked out)
            float p[4];
#pragma unroll
            for (int r = 0; r < 4; r++) {
                float pp = 0.f;
#pragma unroll
                for (int jo = 0; jo < 2; jo++) {
                    int j = jj * 2 + jo;
                    float f = acc_e[at][j][r] + hv[at][j];
                    f = f > 0.f ? f : 0.01f * f;
                    pp = fmaf(f, wv[j], pp);
                }
                pp += __shfl_xor(pp, 1);
                pp += __shfl_xor(pp, 2);
                pp += __shfl_xor(pp, 4);
                pp += __shfl_xor(pp, 8);
                p[r] = (q < 3) ? pp + smask_l[at * KN + q * 4 + r] : -1e30f;
            }
            // softmax over 12 neighbors (cross-q via shfl 16/32)
            float mx = fmaxf(fmaxf(p[0], p[1]), fmaxf(p[2], p[3]));
            mx = fmaxf(mx, __shfl_xor(mx, 16));
            mx = fmaxf(mx, __shfl_xor(mx, 32));
            float ex[4], ss = 0.f;
#pragma unroll
            for (int r = 0; r < 4; r++) {
                ex[r] = (q < 3) ? __expf(p[r] - mx) : 0.f;
                ss += ex[r];
            }
            ss += __shfl_xor(ss, 16);
            ss += __shfl_xor(ss, 32);
            float inv = 1.f / ss;
            float am[4];
#pragma unroll
            for (int r = 0; r < 4; r++)
                am[r] = (q < 3) ? ex[r] * inv * amask_l[at * KN + q * 4 + r] : 0.f;
            // ctx[col] = sum_k attn_k * e_k  (q-reduce via shfl 16/32)
#pragma unroll
            for (int jo = 0; jo < 2; jo++) {
                int j = jj * 2 + jo;
                float cp = am[0] * acc_e[at][j][0] + am[1] * acc_e[at][j][1] +
                           am[2] * acc_e[at][j][2] + am[3] * acc_e[at][j][3];
                cp += __shfl_xor(cp, 16);
                cp += __shfl_xor(cp, 32);
                ctxv[at][j] = cp;
                s1 += cp;
                s2 += cp * cp;
            }
        }
        // LN partial sums: reduce over m-group -> wave total over its 64 cols
#pragma unroll
        for (int off = 1; off < 16; off <<= 1) {
            s1 += __shfl_xor(s1, off);
            s2 += __shfl_xor(s2, off);
        }
        if (l == 0) { red_l[at][w] = s1; red_l[at][4 + w] = s2; }
    }
    __syncthreads();   // barrier 2: LN cross-wave reduce

    // ---- LayerNorm epilogue ----
#pragma unroll
    for (int at = 0; at < ATB; at++) {
        float ts1 = red_l[at][0] + red_l[at][1] + red_l[at][2] + red_l[at][3];
        float ts2 = red_l[at][4] + red_l[at][5] + red_l[at][6] + red_l[at][7];
        float mu = ts1 * (1.f / 256.f);
        float var = ts2 * (1.f / 256.f) - mu * mu;
        var = fmaxf(var, 0.f);
        float rs = rsqrtf(var + 1e-5f);
        if (q == 0) {
#pragma unroll
            for (int j = 0; j < 4; j++) {
                int col = w * 64 + j * 16 + m;
                out[(size_t)(a0 + at) * DNEW + col] =
                    (ctxv[at][j] - mu) * rs * gam[col] + bet[col];
            }
        }
    }
}

extern "C" void kernel_launch(void* const* d_in, const int* in_sizes, int n_in,
                              void* d_out, int out_size, void* d_ws, size_t ws_size,
                              hipStream_t stream) {
    const float* atomf = (const float*)d_in[0];
    const float* nbrf  = (const float*)d_in[1];
    const float* smask = (const float*)d_in[2];
    const float* amask = (const float*)d_in[3];
    const float* Wa    = (const float*)d_in[4];
    const float* ba    = (const float*)d_in[5];
    const float* Wn    = (const float*)d_in[6];
    const float* bnb   = (const float*)d_in[7];
    const float* wal   = (const float*)d_in[8];
    const float* bal   = (const float*)d_in[9];
    const float* gam   = (const float*)d_in[10];
    const float* bet   = (const float*)d_in[11];
    float* outp = (float*)d_out;

    u16* B2 = (u16*)d_ws;                              // 288 KiB
    float* h_g = (float*)((char*)d_ws + H_OFF);        // 8 MiB fp32 h

    build_b2<<<72, 256, 0, stream>>>(Wn, Wa, B2);
    h_pre<<<BN_TOT / 32, 256, 0, stream>>>(atomf, B2, ba, h_g);
    fused_all<<<BN_TOT / ATB, 256, 0, stream>>>(nbrf, smask, amask, B2, h_g,
                                                bnb, wal, bal, gam, bet, outp);
}